// Round 2
// baseline (478.380 us; speedup 1.0000x reference)
//
#include <hip/hip_runtime.h>
#include <stdint.h>

// HealthAttention: out = (softmax(rope(XWq^T) rope(XWk^T)^T / sqrt(128)) XWv^T) Wo^T
// B=2 S=2048 D=2048 H=16 DH=128.  medical_bias is per-head constant over the
// softmax axis -> softmax-invariant -> dropped.
// R2: XOR-swizzled LDS layout in k_attn (K/V/P tiles) to kill the 16-way
// bank conflicts (SQ_LDS_BANK_CONFLICT 4.9e7 -> target <1e7).
// Swizzle: 16B-slot index ^= (row & 7); applied by pre-swizzling the
// global source address for global_load_lds (linear LDS dest) and applying
// the same XOR on all ds_read/ds_write addresses (rule #21).

#define B_ 2
#define S_ 2048
#define D_ 2048
#define H_ 16

typedef float f32x4 __attribute__((ext_vector_type(4)));
typedef short s16x8 __attribute__((ext_vector_type(8)));

__device__ __forceinline__ unsigned short f2bf(float f) {
  union { float f; uint32_t u; } c; c.f = f;
  return (unsigned short)((c.u + 0x7fffu + ((c.u >> 16) & 1u)) >> 16);
}

__device__ __forceinline__ void gld_lds16(const void* g, void* l) {
  __builtin_amdgcn_global_load_lds(
      (const __attribute__((address_space(1))) uint32_t*)g,
      (__attribute__((address_space(3))) uint32_t*)l, 16, 0, 0);
}

// ---------------- fp32 -> bf16 convert ----------------
__global__ __launch_bounds__(256) void k_f2bf(const float* __restrict__ in,
                                              unsigned short* __restrict__ out,
                                              int n4) {
  int i = blockIdx.x * 256 + threadIdx.x;
  int stride = gridDim.x * 256;
  for (; i < n4; i += stride) {
    f32x4 v = ((const f32x4*)in)[i];
    ushort4 o;
    o.x = f2bf(v.x); o.y = f2bf(v.y); o.z = f2bf(v.z); o.w = f2bf(v.w);
    ((ushort4*)out)[i] = o;
  }
}

// ---------------- rope tables: cos/sin [S][64] ----------------
__global__ __launch_bounds__(256) void k_tab(float* __restrict__ tc,
                                             float* __restrict__ ts) {
  int t = blockIdx.x * 256 + threadIdx.x;  // 0..131071
  int s = t >> 6, j = t & 63;
  float inv = expf(-(float)j * (1.0f / 64.0f) * 9.210340371976184f);
  float ang = (float)s * inv;
  float sv, cv;
  sincosf(ang, &sv, &cv);
  tc[t] = cv;
  ts[t] = sv;
}

// ---------------- GEMM: C[M,N] = A[M,K] @ W[N,K]^T  (bf16 in, fp32 acc) -----
// 128x128 tile, BK=64, 4 waves (2x2), 16x16x32 MFMA.
// z=0 -> fp32 to C0; z=1 -> fp32 to C1; z=2 -> bf16 transposed per-head to VT.
__global__ __launch_bounds__(256, 2) void k_gemm(
    const unsigned short* __restrict__ A,
    const unsigned short* __restrict__ W0,
    const unsigned short* __restrict__ W1,
    const unsigned short* __restrict__ W2,
    float* __restrict__ C0,
    float* __restrict__ C1,
    unsigned short* __restrict__ VT) {
  __shared__ unsigned short Al[128 * 64];
  __shared__ unsigned short Bl[128 * 64];

  const int z = blockIdx.z;
  const unsigned short* __restrict__ Wp = (z == 0) ? W0 : (z == 1) ? W1 : W2;

  const int tid = threadIdx.x;
  const int w = tid >> 6;
  const int l = tid & 63;
  const int wr = w >> 1, wc = w & 1;
  const int row0 = (int)blockIdx.y * 128;
  const int col0 = (int)blockIdx.x * 128;

  const int srow = l >> 3;        // staging: 8 rows x 128B per wave-issue
  const int scol = (l & 7) << 3;  // bf16 elems
  const int c16 = l & 15, g = l >> 4;

  f32x4 acc[4][4];
#pragma unroll
  for (int m = 0; m < 4; ++m)
#pragma unroll
    for (int n = 0; n < 4; ++n)
      acc[m][n] = f32x4{0.f, 0.f, 0.f, 0.f};

  for (int k0 = 0; k0 < 2048; k0 += 64) {
#pragma unroll
    for (int i = 0; i < 4; ++i) {
      const int jj = (w << 2) + i;  // 0..15, wave-uniform
      gld_lds16(&A[(size_t)(row0 + (jj << 3) + srow) * 2048 + k0 + scol],
                &Al[jj * 512]);
      gld_lds16(&Wp[(size_t)(col0 + (jj << 3) + srow) * 2048 + k0 + scol],
                &Bl[jj * 512]);
    }
    __syncthreads();
#pragma unroll
    for (int kk = 0; kk < 2; ++kk) {
      const int cc = kk * 32 + g * 8;
      s16x8 a[4], b[4];
#pragma unroll
      for (int m = 0; m < 4; ++m)
        a[m] = *(const s16x8*)&Al[(wr * 64 + m * 16 + c16) * 64 + cc];
#pragma unroll
      for (int n = 0; n < 4; ++n)
        b[n] = *(const s16x8*)&Bl[(wc * 64 + n * 16 + c16) * 64 + cc];
#pragma unroll
      for (int m = 0; m < 4; ++m)
#pragma unroll
        for (int n = 0; n < 4; ++n)
          acc[m][n] =
              __builtin_amdgcn_mfma_f32_16x16x32_bf16(a[m], b[n], acc[m][n], 0, 0, 0);
    }
    __syncthreads();
  }

  if (z < 2) {
    float* __restrict__ C = (z == 0) ? C0 : C1;
#pragma unroll
    for (int m = 0; m < 4; ++m) {
      const int gr = row0 + wr * 64 + m * 16 + g * 4;
#pragma unroll
      for (int n = 0; n < 4; ++n) {
        const int gc = col0 + wc * 64 + n * 16 + c16;
#pragma unroll
        for (int r = 0; r < 4; ++r)
          C[(size_t)(gr + r) * 2048 + gc] = acc[m][n][r];
      }
    }
  } else {
    // V: write bf16 transposed per-head: VT[((b*16+h)*128+dh)*2048 + s]
#pragma unroll
    for (int m = 0; m < 4; ++m) {
      const int gr = row0 + wr * 64 + m * 16 + g * 4;  // 4 consecutive s
      const int b_ = gr >> 11, s_ = gr & 2047;
#pragma unroll
      for (int n = 0; n < 4; ++n) {
        const int gc = col0 + wc * 64 + n * 16 + c16;  // h*128+dh
        ushort4 o;
        o.x = f2bf(acc[m][n][0]);
        o.y = f2bf(acc[m][n][1]);
        o.z = f2bf(acc[m][n][2]);
        o.w = f2bf(acc[m][n][3]);
        *(ushort4*)&VT[((size_t)(b_ * 2048 + gc)) * 2048 + s_] = o;
      }
    }
  }
}

// ---------------- RoPE: fp32 in -> bf16 out; z=0 Q(scaled), z=1 K ----------
__global__ __launch_bounds__(256) void k_rope(const float* __restrict__ Qf,
                                              const float* __restrict__ Kf,
                                              unsigned short* __restrict__ Qb,
                                              unsigned short* __restrict__ Kb,
                                              const float* __restrict__ tc,
                                              const float* __restrict__ ts) {
  const float* __restrict__ in = blockIdx.z ? Kf : Qf;
  unsigned short* __restrict__ out = blockIdx.z ? Kb : Qb;
  const float scale = blockIdx.z ? 1.0f : 0.08838834764831845f;  // 1/sqrt(128)
  int u = blockIdx.x * 256 + threadIdx.x;
  const int total = B_ * S_ * H_ * 16;  // 1048576 quad-units
  for (; u < total; u += gridDim.x * 256) {
    int bs = u >> 8;
    int rem = u & 255;
    int h = rem >> 4, j4 = rem & 15;
    int s = bs & 2047;
    size_t base = (size_t)bs * 2048 + h * 128 + j4 * 4;
    f32x4 x1 = *(const f32x4*)&in[base];
    f32x4 x2 = *(const f32x4*)&in[base + 64];
    f32x4 c = *(const f32x4*)&tc[s * 64 + j4 * 4];
    f32x4 sn = *(const f32x4*)&ts[s * 64 + j4 * 4];
    f32x4 o1 = (x1 * c - x2 * sn) * scale;
    f32x4 o2 = (x2 * c + x1 * sn) * scale;
    ushort4 oa, ob;
    oa.x = f2bf(o1.x); oa.y = f2bf(o1.y); oa.z = f2bf(o1.z); oa.w = f2bf(o1.w);
    ob.x = f2bf(o2.x); ob.y = f2bf(o2.y); ob.z = f2bf(o2.z); ob.w = f2bf(o2.w);
    *(ushort4*)&out[base] = oa;
    *(ushort4*)&out[base + 64] = ob;
  }
}

// ---------------- flash attention (XOR-swizzled LDS) ----------------
// grid (16, 32): x = q-block (128 rows), y = b*16+h. 4 waves x 32 q-rows.
// Swizzle: within each row, 16B-slot index ^= (row & 7).
//  Kl rows = 128 elems = 16 slots; Vl/Pl rows = 64 elems = 8 slots.
__global__ __launch_bounds__(256, 1) void k_attn(
    const unsigned short* __restrict__ Qb,
    const unsigned short* __restrict__ Kb,
    const unsigned short* __restrict__ Vt,
    unsigned short* __restrict__ Ob) {
  __shared__ unsigned short Kl[64 * 128];   // [key][d]   swizzled
  __shared__ unsigned short Vl[128 * 64];   // [d][key]   swizzled
  __shared__ unsigned short Pl[4][32 * 64]; // per-wave P swizzled

  const int tid = threadIdx.x, w = tid >> 6, l = tid & 63;
  const int bh = blockIdx.y;
  const int b = bh >> 4, h = bh & 15;
  const int q0 = (int)blockIdx.x * 128 + w * 32;
  const int g = l >> 4, c16 = l & 15;
  const int cx = c16 & 7;  // row&7 for rows of form n*16+c16

  // Q fragments in registers (scores pre-scaled via Q)
  s16x8 qf[2][4];
#pragma unroll
  for (int qq = 0; qq < 2; ++qq)
#pragma unroll
    for (int kc = 0; kc < 4; ++kc)
      qf[qq][kc] = *(const s16x8*)&Qb[(size_t)(b * 2048 + q0 + qq * 16 + c16) * 2048 +
                                      h * 128 + kc * 32 + g * 8];

  f32x4 oacc[2][8];
  float mrow[2][4], lrow[2][4];
#pragma unroll
  for (int qq = 0; qq < 2; ++qq) {
#pragma unroll
    for (int df = 0; df < 8; ++df) oacc[qq][df] = f32x4{0.f, 0.f, 0.f, 0.f};
#pragma unroll
    for (int r = 0; r < 4; ++r) { mrow[qq][r] = -INFINITY; lrow[qq][r] = 0.f; }
  }

  for (int t = 0; t < 2048; t += 64) {
#pragma unroll
    for (int i = 0; i < 4; ++i) {
      const int jj = (w << 2) + i;  // 0..15, wave-uniform
      // K: LDS row = jj*4 + (l>>4); lane writes slot (l&15) -> source slot
      // pre-swizzled so LDS holds slot^(row&7).
      const int krow = jj * 4 + (l >> 4);
      const int kslot = (l & 15) ^ (krow & 7);
      gld_lds16(&Kb[(size_t)(b * 2048 + t + krow) * 2048 + h * 128 + (kslot << 3)],
                &Kl[jj * 512]);
      // V: LDS row = jj*8 + (l>>3); lane writes slot (l&7).
      const int vrow = jj * 8 + (l >> 3);
      const int vslot = (l & 7) ^ (vrow & 7);
      gld_lds16(&Vt[(size_t)(bh * 128 + vrow) * 2048 + t + (vslot << 3)],
                &Vl[jj * 512]);
    }
    __syncthreads();

    // S = Q K^T  (pre-scaled)
    f32x4 sacc[2][4];
#pragma unroll
    for (int qq = 0; qq < 2; ++qq)
#pragma unroll
      for (int n = 0; n < 4; ++n) sacc[qq][n] = f32x4{0.f, 0.f, 0.f, 0.f};
#pragma unroll
    for (int kc = 0; kc < 4; ++kc) {
      s16x8 kb[4];
#pragma unroll
      for (int n = 0; n < 4; ++n)
        kb[n] = *(const s16x8*)&Kl[(n * 16 + c16) * 128 + (((kc * 4 + g) ^ cx) << 3)];
#pragma unroll
      for (int qq = 0; qq < 2; ++qq)
#pragma unroll
        for (int n = 0; n < 4; ++n)
          sacc[qq][n] =
              __builtin_amdgcn_mfma_f32_16x16x32_bf16(qf[qq][kc], kb[n], sacc[qq][n], 0, 0, 0);
    }

    // online softmax (rows = qq*16 + g*4 + r, cols in lanes c16 x 4 frags)
#pragma unroll
    for (int qq = 0; qq < 2; ++qq) {
#pragma unroll
      for (int r = 0; r < 4; ++r) {
        float mx = fmaxf(fmaxf(sacc[qq][0][r], sacc[qq][1][r]),
                         fmaxf(sacc[qq][2][r], sacc[qq][3][r]));
        mx = fmaxf(mx, __shfl_xor(mx, 1));
        mx = fmaxf(mx, __shfl_xor(mx, 2));
        mx = fmaxf(mx, __shfl_xor(mx, 4));
        mx = fmaxf(mx, __shfl_xor(mx, 8));
        float mnew = fmaxf(mrow[qq][r], mx);
        float alpha = __expf(mrow[qq][r] - mnew);
        mrow[qq][r] = mnew;
        float rs = 0.f;
#pragma unroll
        for (int n = 0; n < 4; ++n) {
          float p = __expf(sacc[qq][n][r] - mnew);
          sacc[qq][n][r] = p;
          rs += p;
        }
        rs += __shfl_xor(rs, 1);
        rs += __shfl_xor(rs, 2);
        rs += __shfl_xor(rs, 4);
        rs += __shfl_xor(rs, 8);
        lrow[qq][r] = lrow[qq][r] * alpha + rs;
#pragma unroll
        for (int df = 0; df < 8; ++df) oacc[qq][df][r] *= alpha;
      }
      // P -> per-wave LDS (bf16), swizzled: slot = (n*2 + c16>>3) ^ (row&7)
#pragma unroll
      for (int n = 0; n < 4; ++n)
#pragma unroll
        for (int r = 0; r < 4; ++r) {
          const int prow = qq * 16 + g * 4 + r;
          const int psl = (n * 2 + (c16 >> 3)) ^ (prow & 7);
          Pl[w][prow * 64 + (psl << 3) + (c16 & 7)] = f2bf(sacc[qq][n][r]);
        }
    }

    // O += P V   (P: [q][k], V from Vl: [d][k])
#pragma unroll
    for (int kc2 = 0; kc2 < 2; ++kc2) {
      s16x8 pa[2];
#pragma unroll
      for (int qq = 0; qq < 2; ++qq)
        pa[qq] = *(const s16x8*)&Pl[w][(qq * 16 + c16) * 64 + (((kc2 * 4 + g) ^ cx) << 3)];
#pragma unroll
      for (int df = 0; df < 8; ++df) {
        s16x8 vb = *(const s16x8*)&Vl[(df * 16 + c16) * 64 + (((kc2 * 4 + g) ^ cx) << 3)];
#pragma unroll
        for (int qq = 0; qq < 2; ++qq)
          oacc[qq][df] =
              __builtin_amdgcn_mfma_f32_16x16x32_bf16(pa[qq], vb, oacc[qq][df], 0, 0, 0);
      }
    }
    __syncthreads();
  }

  // epilogue: divide by softmax denom, write bf16 [B,S,D]
#pragma unroll
  for (int qq = 0; qq < 2; ++qq)
#pragma unroll
    for (int r = 0; r < 4; ++r) {
      const float inv = 1.0f / lrow[qq][r];
      const int srow_ = q0 + qq * 16 + g * 4 + r;
#pragma unroll
      for (int df = 0; df < 8; ++df)
        Ob[(size_t)(b * 2048 + srow_) * 2048 + h * 128 + df * 16 + c16] =
            f2bf(oacc[qq][df][r] * inv);
    }
}

// ---------------- launch ----------------
extern "C" void kernel_launch(void* const* d_in, const int* in_sizes, int n_in,
                              void* d_out, int out_size, void* d_ws, size_t ws_size,
                              hipStream_t stream) {
  const float* hs = (const float*)d_in[0];
  const float* Wq = (const float*)d_in[1];
  const float* Wk = (const float*)d_in[2];
  const float* Wv = (const float*)d_in[3];
  const float* Wo = (const float*)d_in[4];
  // d_in[5] medical_bias: per-head constant over softmax axis -> no-op.
  float* out = (float*)d_out;
  char* ws = (char*)d_ws;

  // workspace layout (bytes)
  unsigned short* hb  = (unsigned short*)(ws + 0);          // 16.78 MB (reused as Ob)
  unsigned short* wqb = (unsigned short*)(ws + 16777216);   // 8.39 MB
  unsigned short* wkb = (unsigned short*)(ws + 25165824);
  unsigned short* wvb = (unsigned short*)(ws + 33554432);
  unsigned short* wob = (unsigned short*)(ws + 41943040);
  float*          Qf  = (float*)(ws + 50331648);            // 33.55 MB
  float*          Kf  = (float*)(ws + 83886080);
  unsigned short* Vt  = (unsigned short*)(ws + 117440512);  // 16.78 MB
  unsigned short* Qbb = (unsigned short*)(ws + 134217728);
  unsigned short* Kbb = (unsigned short*)(ws + 150994944);
  float*          tabc = (float*)(ws + 167772160);          // 512 KB
  float*          tabs = (float*)(ws + 168296448);
  unsigned short* Ob  = hb;  // hidden-bf16 region reused after QKV GEMM

  k_f2bf<<<1024, 256, 0, stream>>>(hs, hb, 2097152);
  k_f2bf<<<1024, 256, 0, stream>>>(Wq, wqb, 1048576);
  k_f2bf<<<1024, 256, 0, stream>>>(Wk, wkb, 1048576);
  k_f2bf<<<1024, 256, 0, stream>>>(Wv, wvb, 1048576);
  k_f2bf<<<1024, 256, 0, stream>>>(Wo, wob, 1048576);
  k_tab<<<512, 256, 0, stream>>>(tabc, tabs);

  k_gemm<<<dim3(16, 32, 3), 256, 0, stream>>>(hb, wqb, wkb, wvb, Qf, Kf, Vt);
  k_rope<<<dim3(1024, 1, 2), 256, 0, stream>>>(Qf, Kf, Qbb, Kbb, tabc, tabs);
  k_attn<<<dim3(16, 32), 256, 0, stream>>>(Qbb, Kbb, Vt, Ob);
  k_gemm<<<dim3(16, 32, 1), 256, 0, stream>>>(Ob, wob, nullptr, nullptr, out,
                                              nullptr, nullptr);
}

// Round 3
// 365.354 us; speedup vs baseline: 1.3094x; 1.3094x over previous
//
#include <hip/hip_runtime.h>
#include <stdint.h>

// HealthAttention: out = (softmax(rope(XWq^T) rope(XWk^T)^T / sqrt(128)) XWv^T) Wo^T
// B=2 S=2048 D=2048 H=16 DH=128.  medical_bias is per-head constant over the
// softmax axis -> softmax-invariant -> dropped.
// R3: k_attn restructured to T3-minimum pipeline: double-buffered K/V LDS,
// STAGE(t+1) issued before COMPUTE(t), ONE barrier per tile. Swizzled LDS
// kept (regime gate now satisfied), read addresses hoisted to lane-only
// registers (ds_read offsets stay immediates). setprio(1) around MFMA
// clusters (T5). Bijective XCD swizzle (T1) on k_attn and k_gemm grids.

#define B_ 2
#define S_ 2048
#define D_ 2048
#define H_ 16

typedef float f32x4 __attribute__((ext_vector_type(4)));
typedef short s16x8 __attribute__((ext_vector_type(8)));

__device__ __forceinline__ unsigned short f2bf(float f) {
  union { float f; uint32_t u; } c; c.f = f;
  return (unsigned short)((c.u + 0x7fffu + ((c.u >> 16) & 1u)) >> 16);
}

__device__ __forceinline__ void gld_lds16(const void* g, void* l) {
  __builtin_amdgcn_global_load_lds(
      (const __attribute__((address_space(1))) uint32_t*)g,
      (__attribute__((address_space(3))) uint32_t*)l, 16, 0, 0);
}

// ---------------- fp32 -> bf16 convert ----------------
__global__ __launch_bounds__(256) void k_f2bf(const float* __restrict__ in,
                                              unsigned short* __restrict__ out,
                                              int n4) {
  int i = blockIdx.x * 256 + threadIdx.x;
  int stride = gridDim.x * 256;
  for (; i < n4; i += stride) {
    f32x4 v = ((const f32x4*)in)[i];
    ushort4 o;
    o.x = f2bf(v.x); o.y = f2bf(v.y); o.z = f2bf(v.z); o.w = f2bf(v.w);
    ((ushort4*)out)[i] = o;
  }
}

// ---------------- rope tables: cos/sin [S][64] ----------------
__global__ __launch_bounds__(256) void k_tab(float* __restrict__ tc,
                                             float* __restrict__ ts) {
  int t = blockIdx.x * 256 + threadIdx.x;  // 0..131071
  int s = t >> 6, j = t & 63;
  float inv = expf(-(float)j * (1.0f / 64.0f) * 9.210340371976184f);
  float ang = (float)s * inv;
  float sv, cv;
  sincosf(ang, &sv, &cv);
  tc[t] = cv;
  ts[t] = sv;
}

// ---------------- GEMM: C[M,N] = A[M,K] @ W[N,K]^T  (bf16 in, fp32 acc) -----
// 128x128 tile, BK=64, 4 waves (2x2), 16x16x32 MFMA. XCD-swizzled grid.
// z=0 -> fp32 to C0; z=1 -> fp32 to C1; z=2 -> bf16 transposed per-head to VT.
__global__ __launch_bounds__(256, 2) void k_gemm(
    const unsigned short* __restrict__ A,
    const unsigned short* __restrict__ W0,
    const unsigned short* __restrict__ W1,
    const unsigned short* __restrict__ W2,
    float* __restrict__ C0,
    float* __restrict__ C1,
    unsigned short* __restrict__ VT) {
  __shared__ unsigned short Al[128 * 64];
  __shared__ unsigned short Bl[128 * 64];

  // bijective XCD remap: hw linear id (x fastest, z slowest), nwg % 8 == 0
  const int l0 = ((int)blockIdx.z * 32 + (int)blockIdx.y) * 16 + (int)blockIdx.x;
  const int qx = ((int)gridDim.z * 512) >> 3;  // blocks per XCD
  const int wg = (l0 & 7) * qx + (l0 >> 3);
  const int z = wg >> 9;
  const unsigned short* __restrict__ Wp = (z == 0) ? W0 : (z == 1) ? W1 : W2;

  const int tid = threadIdx.x;
  const int w = tid >> 6;
  const int l = tid & 63;
  const int wr = w >> 1, wc = w & 1;
  const int row0 = ((wg >> 4) & 31) * 128;
  const int col0 = (wg & 15) * 128;

  const int srow = l >> 3;        // staging: 8 rows x 128B per wave-issue
  const int scol = (l & 7) << 3;  // bf16 elems
  const int c16 = l & 15, g = l >> 4;

  f32x4 acc[4][4];
#pragma unroll
  for (int m = 0; m < 4; ++m)
#pragma unroll
    for (int n = 0; n < 4; ++n)
      acc[m][n] = f32x4{0.f, 0.f, 0.f, 0.f};

  for (int k0 = 0; k0 < 2048; k0 += 64) {
#pragma unroll
    for (int i = 0; i < 4; ++i) {
      const int jj = (w << 2) + i;  // 0..15, wave-uniform
      gld_lds16(&A[(size_t)(row0 + (jj << 3) + srow) * 2048 + k0 + scol],
                &Al[jj * 512]);
      gld_lds16(&Wp[(size_t)(col0 + (jj << 3) + srow) * 2048 + k0 + scol],
                &Bl[jj * 512]);
    }
    __syncthreads();
#pragma unroll
    for (int kk = 0; kk < 2; ++kk) {
      const int cc = kk * 32 + g * 8;
      s16x8 a[4], b[4];
#pragma unroll
      for (int m = 0; m < 4; ++m)
        a[m] = *(const s16x8*)&Al[(wr * 64 + m * 16 + c16) * 64 + cc];
#pragma unroll
      for (int n = 0; n < 4; ++n)
        b[n] = *(const s16x8*)&Bl[(wc * 64 + n * 16 + c16) * 64 + cc];
#pragma unroll
      for (int m = 0; m < 4; ++m)
#pragma unroll
        for (int n = 0; n < 4; ++n)
          acc[m][n] =
              __builtin_amdgcn_mfma_f32_16x16x32_bf16(a[m], b[n], acc[m][n], 0, 0, 0);
    }
    __syncthreads();
  }

  if (z < 2) {
    float* __restrict__ C = (z == 0) ? C0 : C1;
#pragma unroll
    for (int m = 0; m < 4; ++m) {
      const int gr = row0 + wr * 64 + m * 16 + g * 4;
#pragma unroll
      for (int n = 0; n < 4; ++n) {
        const int gc = col0 + wc * 64 + n * 16 + c16;
#pragma unroll
        for (int r = 0; r < 4; ++r)
          C[(size_t)(gr + r) * 2048 + gc] = acc[m][n][r];
      }
    }
  } else {
    // V: write bf16 transposed per-head: VT[((b*16+h)*128+dh)*2048 + s]
#pragma unroll
    for (int m = 0; m < 4; ++m) {
      const int gr = row0 + wr * 64 + m * 16 + g * 4;  // 4 consecutive s
      const int b_ = gr >> 11, s_ = gr & 2047;
#pragma unroll
      for (int n = 0; n < 4; ++n) {
        const int gc = col0 + wc * 64 + n * 16 + c16;  // h*128+dh
        ushort4 o;
        o.x = f2bf(acc[m][n][0]);
        o.y = f2bf(acc[m][n][1]);
        o.z = f2bf(acc[m][n][2]);
        o.w = f2bf(acc[m][n][3]);
        *(ushort4*)&VT[((size_t)(b_ * 2048 + gc)) * 2048 + s_] = o;
      }
    }
  }
}

// ---------------- RoPE: fp32 in -> bf16 out; z=0 Q(scaled), z=1 K ----------
__global__ __launch_bounds__(256) void k_rope(const float* __restrict__ Qf,
                                              const float* __restrict__ Kf,
                                              unsigned short* __restrict__ Qb,
                                              unsigned short* __restrict__ Kb,
                                              const float* __restrict__ tc,
                                              const float* __restrict__ ts) {
  const float* __restrict__ in = blockIdx.z ? Kf : Qf;
  unsigned short* __restrict__ out = blockIdx.z ? Kb : Qb;
  const float scale = blockIdx.z ? 1.0f : 0.08838834764831845f;  // 1/sqrt(128)
  int u = blockIdx.x * 256 + threadIdx.x;
  const int total = B_ * S_ * H_ * 16;  // 1048576 quad-units
  for (; u < total; u += gridDim.x * 256) {
    int bs = u >> 8;
    int rem = u & 255;
    int h = rem >> 4, j4 = rem & 15;
    int s = bs & 2047;
    size_t base = (size_t)bs * 2048 + h * 128 + j4 * 4;
    f32x4 x1 = *(const f32x4*)&in[base];
    f32x4 x2 = *(const f32x4*)&in[base + 64];
    f32x4 c = *(const f32x4*)&tc[s * 64 + j4 * 4];
    f32x4 sn = *(const f32x4*)&ts[s * 64 + j4 * 4];
    f32x4 o1 = (x1 * c - x2 * sn) * scale;
    f32x4 o2 = (x2 * c + x1 * sn) * scale;
    ushort4 oa, ob;
    oa.x = f2bf(o1.x); oa.y = f2bf(o1.y); oa.z = f2bf(o1.z); oa.w = f2bf(o1.w);
    ob.x = f2bf(o2.x); ob.y = f2bf(o2.y); ob.z = f2bf(o2.z); ob.w = f2bf(o2.w);
    *(ushort4*)&out[base] = oa;
    *(ushort4*)&out[base + 64] = ob;
  }
}

// ---------------- flash attention (pipelined, swizzled LDS) ----------------
// grid (16, 32): 512 blocks, XCD-remapped so each (b,h) lives on one XCD.
// 4 waves x 32 q-rows; K/V double-buffered; 1 barrier per 64-key tile.
__global__ __launch_bounds__(256, 2) void k_attn(
    const unsigned short* __restrict__ Qb,
    const unsigned short* __restrict__ Kb,
    const unsigned short* __restrict__ Vt,
    unsigned short* __restrict__ Ob) {
  __shared__ unsigned short Kl[2][64 * 128];   // [key][d]  swizzled, 2x16KB
  __shared__ unsigned short Vl[2][128 * 64];   // [d][key]  swizzled, 2x16KB
  __shared__ unsigned short Pl[4][32 * 64];    // per-wave P, swizzled, 16KB

  // bijective XCD remap: 512 blocks -> 64 per XCD; one (b,h) = 16 blocks
  // stays entirely within one XCD (1MB K/V panel -> L2-resident).
  const int l0 = (int)blockIdx.y * 16 + (int)blockIdx.x;
  const int wg = (l0 & 7) * 64 + (l0 >> 3);
  const int bh = wg >> 4;
  const int b = bh >> 4, h = bh & 15;

  const int tid = threadIdx.x, w = tid >> 6, l = tid & 63;
  const int q0 = (wg & 15) * 128 + w * 32;
  const int g = l >> 4, c16 = l & 15;
  const int cx = c16 & 7;  // row&7 for rows of form n*16+c16

  // hoisted swizzled LDS read offsets (bytes, lane-only -> loop offsets fold
  // into ds_read immediates across both buffers)
  int kaddr[4], vaddr[2];
#pragma unroll
  for (int kc = 0; kc < 4; ++kc)
    kaddr[kc] = c16 * 256 + ((((kc * 4 + g) ^ cx)) << 4);
#pragma unroll
  for (int kc2 = 0; kc2 < 2; ++kc2)
    vaddr[kc2] = c16 * 128 + ((((kc2 * 4 + g) ^ cx)) << 4);
  const char* PW = (const char*)&Pl[w][0];

  // Q fragments in registers (scores pre-scaled via Q)
  s16x8 qf[2][4];
#pragma unroll
  for (int qq = 0; qq < 2; ++qq)
#pragma unroll
    for (int kc = 0; kc < 4; ++kc)
      qf[qq][kc] = *(const s16x8*)&Qb[(size_t)(b * 2048 + q0 + qq * 16 + c16) * 2048 +
                                      h * 128 + kc * 32 + g * 8];

  f32x4 oacc[2][8];
  float mrow[2][4], lrow[2][4];
#pragma unroll
  for (int qq = 0; qq < 2; ++qq) {
#pragma unroll
    for (int df = 0; df < 8; ++df) oacc[qq][df] = f32x4{0.f, 0.f, 0.f, 0.f};
#pragma unroll
    for (int r = 0; r < 4; ++r) { mrow[qq][r] = -INFINITY; lrow[qq][r] = 0.f; }
  }

#define STAGE(T, BUF)                                                          \
  do {                                                                         \
    _Pragma("unroll") for (int i = 0; i < 4; ++i) {                            \
      const int jj = (w << 2) + i;                                             \
      const int krow = jj * 4 + (l >> 4);                                      \
      const int kslot = (l & 15) ^ (krow & 7);                                 \
      gld_lds16(&Kb[(size_t)(b * 2048 + (T) + krow) * 2048 + h * 128 +        \
                    (kslot << 3)],                                             \
                &Kl[BUF][jj * 512]);                                           \
      const int vrow = jj * 8 + (l >> 3);                                      \
      const int vslot = (l & 7) ^ (vrow & 7);                                  \
      gld_lds16(&Vt[(size_t)(bh * 128 + vrow) * 2048 + (T) + (vslot << 3)],    \
                &Vl[BUF][jj * 512]);                                           \
    }                                                                          \
  } while (0)

#define COMPUTE(BUF_)                                                          \
  do {                                                                         \
    f32x4 sacc[2][4];                                                          \
    _Pragma("unroll") for (int qq = 0; qq < 2; ++qq)                           \
        _Pragma("unroll") for (int n = 0; n < 4; ++n)                          \
            sacc[qq][n] = f32x4{0.f, 0.f, 0.f, 0.f};                           \
    const char* KB = (const char*)&Kl[BUF_][0];                                \
    __builtin_amdgcn_s_setprio(1);                                             \
    _Pragma("unroll") for (int kc = 0; kc < 4; ++kc) {                         \
      s16x8 kb[4];                                                             \
      _Pragma("unroll") for (int n = 0; n < 4; ++n)                            \
          kb[n] = *(const s16x8*)(KB + kaddr[kc] + n * 4096);                  \
      _Pragma("unroll") for (int qq = 0; qq < 2; ++qq)                         \
          _Pragma("unroll") for (int n = 0; n < 4; ++n)                        \
              sacc[qq][n] = __builtin_amdgcn_mfma_f32_16x16x32_bf16(           \
                  qf[qq][kc], kb[n], sacc[qq][n], 0, 0, 0);                    \
    }                                                                          \
    __builtin_amdgcn_s_setprio(0);                                             \
    _Pragma("unroll") for (int qq = 0; qq < 2; ++qq) {                         \
      _Pragma("unroll") for (int r = 0; r < 4; ++r) {                          \
        float mx = fmaxf(fmaxf(sacc[qq][0][r], sacc[qq][1][r]),                \
                         fmaxf(sacc[qq][2][r], sacc[qq][3][r]));               \
        mx = fmaxf(mx, __shfl_xor(mx, 1));                                     \
        mx = fmaxf(mx, __shfl_xor(mx, 2));                                     \
        mx = fmaxf(mx, __shfl_xor(mx, 4));                                     \
        mx = fmaxf(mx, __shfl_xor(mx, 8));                                     \
        float mnew = fmaxf(mrow[qq][r], mx);                                   \
        float alpha = __expf(mrow[qq][r] - mnew);                              \
        mrow[qq][r] = mnew;                                                    \
        float rs = 0.f;                                                        \
        _Pragma("unroll") for (int n = 0; n < 4; ++n) {                        \
          float p = __expf(sacc[qq][n][r] - mnew);                             \
          sacc[qq][n][r] = p;                                                  \
          rs += p;                                                             \
        }                                                                      \
        rs += __shfl_xor(rs, 1);                                               \
        rs += __shfl_xor(rs, 2);                                               \
        rs += __shfl_xor(rs, 4);                                               \
        rs += __shfl_xor(rs, 8);                                               \
        lrow[qq][r] = lrow[qq][r] * alpha + rs;                                \
        _Pragma("unroll") for (int df = 0; df < 8; ++df)                       \
            oacc[qq][df][r] *= alpha;                                          \
      }                                                                        \
      _Pragma("unroll") for (int n = 0; n < 4; ++n)                            \
          _Pragma("unroll") for (int r = 0; r < 4; ++r) {                      \
        const int prow = qq * 16 + g * 4 + r;                                  \
        const int psl = (n * 2 + (c16 >> 3)) ^ (prow & 7);                     \
        Pl[w][prow * 64 + (psl << 3) + (c16 & 7)] = f2bf(sacc[qq][n][r]);      \
      }                                                                        \
    }                                                                          \
    const char* VB = (const char*)&Vl[BUF_][0];                                \
    __builtin_amdgcn_s_setprio(1);                                             \
    _Pragma("unroll") for (int kc2 = 0; kc2 < 2; ++kc2) {                      \
      s16x8 pa[2];                                                             \
      pa[0] = *(const s16x8*)(PW + vaddr[kc2]);                                \
      pa[1] = *(const s16x8*)(PW + vaddr[kc2] + 2048);                         \
      _Pragma("unroll") for (int df = 0; df < 8; ++df) {                       \
        s16x8 vb = *(const s16x8*)(VB + vaddr[kc2] + df * 2048);               \
        oacc[0][df] = __builtin_amdgcn_mfma_f32_16x16x32_bf16(pa[0], vb,       \
                                                              oacc[0][df], 0, 0, 0); \
        oacc[1][df] = __builtin_amdgcn_mfma_f32_16x16x32_bf16(pa[1], vb,       \
                                                              oacc[1][df], 0, 0, 0); \
      }                                                                        \
    }                                                                          \
    __builtin_amdgcn_s_setprio(0);                                             \
  } while (0)

  STAGE(0, 0);
  __syncthreads();
  for (int t = 0; t < 2048; t += 128) {
    STAGE(t + 64, 1);     // prefetch next tile while computing current
    COMPUTE(0);
    __syncthreads();      // drains vmcnt -> buf1 ready, buf0 free
    if (t + 128 < 2048) STAGE(t + 128, 0);
    COMPUTE(1);
    __syncthreads();
  }
#undef STAGE
#undef COMPUTE

  // epilogue: divide by softmax denom, write bf16 [B,S,D]
#pragma unroll
  for (int qq = 0; qq < 2; ++qq)
#pragma unroll
    for (int r = 0; r < 4; ++r) {
      const float inv = 1.0f / lrow[qq][r];
      const int srow_ = q0 + qq * 16 + g * 4 + r;
#pragma unroll
      for (int df = 0; df < 8; ++df)
        Ob[(size_t)(b * 2048 + srow_) * 2048 + h * 128 + df * 16 + c16] =
            f2bf(oacc[qq][df][r] * inv);
    }
}

// ---------------- launch ----------------
extern "C" void kernel_launch(void* const* d_in, const int* in_sizes, int n_in,
                              void* d_out, int out_size, void* d_ws, size_t ws_size,
                              hipStream_t stream) {
  const float* hs = (const float*)d_in[0];
  const float* Wq = (const float*)d_in[1];
  const float* Wk = (const float*)d_in[2];
  const float* Wv = (const float*)d_in[3];
  const float* Wo = (const float*)d_in[4];
  // d_in[5] medical_bias: per-head constant over softmax axis -> no-op.
  float* out = (float*)d_out;
  char* ws = (char*)d_ws;

  // workspace layout (bytes)
  unsigned short* hb  = (unsigned short*)(ws + 0);          // 16.78 MB (reused as Ob)
  unsigned short* wqb = (unsigned short*)(ws + 16777216);   // 8.39 MB
  unsigned short* wkb = (unsigned short*)(ws + 25165824);
  unsigned short* wvb = (unsigned short*)(ws + 33554432);
  unsigned short* wob = (unsigned short*)(ws + 41943040);
  float*          Qf  = (float*)(ws + 50331648);            // 33.55 MB
  float*          Kf  = (float*)(ws + 83886080);
  unsigned short* Vt  = (unsigned short*)(ws + 117440512);  // 16.78 MB
  unsigned short* Qbb = (unsigned short*)(ws + 134217728);
  unsigned short* Kbb = (unsigned short*)(ws + 150994944);
  float*          tabc = (float*)(ws + 167772160);          // 512 KB
  float*          tabs = (float*)(ws + 168296448);
  unsigned short* Ob  = hb;  // hidden-bf16 region reused after QKV GEMM

  k_f2bf<<<1024, 256, 0, stream>>>(hs, hb, 2097152);
  k_f2bf<<<1024, 256, 0, stream>>>(Wq, wqb, 1048576);
  k_f2bf<<<1024, 256, 0, stream>>>(Wk, wkb, 1048576);
  k_f2bf<<<1024, 256, 0, stream>>>(Wv, wvb, 1048576);
  k_f2bf<<<1024, 256, 0, stream>>>(Wo, wob, 1048576);
  k_tab<<<512, 256, 0, stream>>>(tabc, tabs);

  k_gemm<<<dim3(16, 32, 3), 256, 0, stream>>>(hb, wqb, wkb, wvb, Qf, Kf, Vt);
  k_rope<<<dim3(1024, 1, 2), 256, 0, stream>>>(Qf, Kf, Qbb, Kbb, tabc, tabs);
  k_attn<<<dim3(16, 32), 256, 0, stream>>>(Qbb, Kbb, Vt, Ob);
  k_gemm<<<dim3(16, 32, 1), 256, 0, stream>>>(Ob, wob, nullptr, nullptr, out,
                                              nullptr, nullptr);
}